// Round 6
// baseline (33143.323 us; speedup 1.0000x reference)
//
#include <hip/hip_runtime.h>

// Problem constants
#define BB 16
#define SS 2048
#define DD 256
#define ND4 1024   // 4*D
#define PRD 16     // R-buffer slot depth
#define PGD 8      // GX-buffer slot depth

typedef __attribute__((ext_vector_type(8))) _Float16 half8;
typedef __attribute__((ext_vector_type(4))) float f32x4;
typedef unsigned long long u64;
union H8 { half8 v; unsigned u[4]; uint4 q; };

__device__ __forceinline__ u64 aload(const u64* p) {
    return __hip_atomic_load(p, __ATOMIC_RELAXED, __HIP_MEMORY_SCOPE_AGENT);
}
__device__ __forceinline__ void astore(u64* p, u64 v) {
    __hip_atomic_store(p, v, __ATOMIC_RELAXED, __HIP_MEMORY_SCOPE_AGENT);
}
__device__ __forceinline__ unsigned pload(const unsigned* p) {
    return __hip_atomic_load(p, __ATOMIC_RELAXED, __HIP_MEMORY_SCOPE_AGENT);
}
__device__ __forceinline__ void pstore(unsigned* p, unsigned v) {
    __hip_atomic_store(p, v, __ATOMIC_RELAXED, __HIP_MEMORY_SCOPE_AGENT);
}
__device__ __forceinline__ int aflag(int* p) {
    return __hip_atomic_load(p, __ATOMIC_RELAXED, __HIP_MEMORY_SCOPE_AGENT);
}
__device__ __forceinline__ void sflag(int* p) {
    __hip_atomic_store(p, 1, __ATOMIC_RELAXED, __HIP_MEMORY_SCOPE_AGENT);
}
__device__ __forceinline__ unsigned short f16b(float x) {
    union { _Float16 h; unsigned short u; } c; c.h = (_Float16)x; return c.u;
}
__device__ __forceinline__ bool spinBail(int& guard, int* af) {
    if ((++guard & 63) == 0) {
        __builtin_amdgcn_s_sleep(1);
        if (guard > (1 << 18) || aflag(af)) { sflag(af); return true; }
    }
    return false;
}

// ---------------------------------------------------------------------------
// embed: h0 = [x | tf] @ in_W + in_b
// ---------------------------------------------------------------------------
__global__ void embed_kernel(const float* __restrict__ x, const float* __restrict__ tf,
                             const float* __restrict__ inW, const float* __restrict__ inb,
                             float* __restrict__ h) {
    int tok = blockIdx.x, d = threadIdx.x;
    float xv = x[tok];
    float acc = inb[d] + xv * inW[d];
#pragma unroll
    for (int c = 0; c < 6; ++c)
        acc = fmaf(tf[tok * 6 + c], inW[(c + 1) * DD + d], acc);
    h[(size_t)tok * DD + d] = acc;
}

// ---------------------------------------------------------------------------
// W[4][256][1024] fp32 -> fp16 B-fragment order:
// out[((l*64+G)*8+kc)*64 + lane][8]; elem i = W[l][kc*32+quad*8+i][G*16+mm]
// (used for both Wx and Wh)
// ---------------------------------------------------------------------------
__global__ void wprep_kernel(const float* __restrict__ W, unsigned short* __restrict__ Wo) {
    int l = blockIdx.x >> 6, G = blockIdx.x & 63;
    int lane = threadIdx.x, quad = lane >> 4, mm = lane & 15;
    const float* Wl = W + (size_t)l * DD * ND4;
    unsigned short* o = Wo + (size_t)blockIdx.x * 4096;
#pragma unroll
    for (int kc = 0; kc < 8; ++kc) {
        __align__(16) unsigned short tmp[8];
#pragma unroll
        for (int i = 0; i < 8; ++i)
            tmp[i] = f16b(Wl[(size_t)(kc * 32 + quad * 8 + i) * ND4 + G * 16 + mm]);
        *(uint4*)(o + ((size_t)kc * 64 + lane) * 8) = *(uint4*)tmp;
    }
}

// ---------------------------------------------------------------------------
// Mega kernel, ring-of-2 redesign. 48 WGs x 512 threads:
//   bid 0..3   : scan (l=bid,   s=0)   d in [0,128)
//   bid 8..11  : scan (l=bid-8, s=1)   d in [128,256)   (bid pairing l / l+8:
//                round-robin %8 XCD placement likely co-locates the pair)
//   bid 4..7, 12..15 : idle
//   bid 16..47 : helper (l=idx&3, cg=(idx>>2)&3, j=(idx>>4)&1): weight-
//                stationary gx GEMM, cols [256cg,256cg+256), tokens t%2==j.
// Dataflow: tagged u64 atoms (tag|payload, fence-free), cacheline-private
// publish regions per writer, slot reuse gated by prog counters.
// ---------------------------------------------------------------------------
__global__ __launch_bounds__(512, 1) void mega_kernel(
    const float* __restrict__ hemb, const unsigned short* __restrict__ Whh,
    const unsigned short* __restrict__ Wxh,
    const float* __restrict__ lng, const float* __restrict__ lnb,
    const float* __restrict__ bgp, float* __restrict__ hout,
    u64* __restrict__ Xbuf, u64* __restrict__ Rbuf, u64* __restrict__ GXbuf,
    unsigned* __restrict__ prog, int* __restrict__ abortFlag) {
    __shared__ __align__(16) char blob[67584];
    const int bid = blockIdx.x;
    const int tid = threadIdx.x;

    if (bid < 16) {
        if ((bid & 7) >= 4) return;  // idle pads (XCD-pairing layout)
        // ================= SCAN ROLE =================
        const int l = bid & 3, s = bid >> 3;
        const int wv = tid >> 6, lane = tid & 63;
        const int mm = lane & 15, quad = lane >> 4;
        const int b = tid >> 5, jj = tid & 31;
        const int dbase = 128 * s + 4 * jj;   // global d of this thread's 4 elems
        float (*gbuf)[4][16][132] = (float (*)[4][16][132])blob;  // [par][gate][b][d']

        // B-frags: 4 tiles (gates 0..3), d'-tile = wv
        H8 bfr[4][8];
#pragma unroll
        for (int gam = 0; gam < 4; ++gam) {
            const unsigned short* bp =
                Whh + (size_t)(l * 64 + gam * 16 + 8 * s + wv) * 4096 + (size_t)lane * 8;
#pragma unroll
            for (int kc = 0; kc < 8; ++kc) bfr[gam][kc].q = *(const uint4*)(bp + (size_t)kc * 512);
        }

        float c_[4] = {0.f, 0.f, 0.f, 0.f}, n_[4] = {0.f, 0.f, 0.f, 0.f},
              m_[4] = {0.f, 0.f, 0.f, 0.f};

        u64* Xl = Xbuf + (size_t)l * 4096;
        const u64* Rprev = Rbuf + (size_t)(l > 0 ? l - 1 : 0) * PRD * 4096;
        u64* Rcur = Rbuf + (size_t)(l < 3 ? l : 0) * PRD * 4096;
        u64* GXl = GXbuf + (size_t)l * PGD * 16384;

        // publisher atom slot (2 consecutive atoms: pairs (d,d+1),(d+2,d+3))
        const int kcP = dbase >> 5, quadP = (dbase >> 3) & 3, pP = (dbase & 7) >> 1;
        const size_t xPub = (size_t)kcP * 256 + (size_t)quadP * 64 + (size_t)b * 4 + pP;
        const size_t rdB = (size_t)quad * 64 + (size_t)mm * 4;
        const int kcOwn = 4 * s, kcOth = 4 * (1 - s);

        const size_t gxOff = (size_t)b * 1024 + dbase;
        const size_t rOff = (size_t)b * 256 + dbase;
        const float* hembP = hemb + (size_t)b * SS * DD + dbase;
        float* houtP = hout + (size_t)b * SS * DD + dbase;
        const unsigned* consSP = prog + (l + 1) * 2;      // scan l+1 pair
        const unsigned* consHP = prog + 8 + (l + 1) * 8;  // helpers l+1 (8)
        unsigned consS = 0, consH = 0;
        unsigned* myProg = prog + l * 2 + s;
        __syncthreads();

        for (int t = 0; t < SS; ++t) {
            const unsigned tagT = (unsigned)(t + 1);
            // ---- early-issue GX (+R) acquire loads ----
            const u64* Gp = GXl + (size_t)(t & (PGD - 1)) * 16384 + gxOff;
            const u64* Rp = Rprev + (size_t)(t & (PRD - 1)) * 4096 + rOff;
            u64 ga[16];
#pragma unroll
            for (int gam = 0; gam < 4; ++gam)
#pragma unroll
                for (int e = 0; e < 4; ++e) ga[gam * 4 + e] = aload(Gp + gam * 256 + e);
            u64 ar[4] = {0, 0, 0, 0};
            float hin4[4] = {0.f, 0.f, 0.f, 0.f};
            if (l > 0) {
#pragma unroll
                for (int e = 0; e < 4; ++e) ar[e] = aload(Rp + e);
            } else {
                float4 hv = *(const float4*)(hembP + (size_t)t * DD);
                hin4[0] = hv.x; hin4[1] = hv.y; hin4[2] = hv.z; hin4[3] = hv.w;
            }

            // ---- X rendezvous: own half first (overlap MFMA with partner RTT) ----
            f32x4 acc[4] = {{0.f, 0.f, 0.f, 0.f}, {0.f, 0.f, 0.f, 0.f},
                            {0.f, 0.f, 0.f, 0.f}, {0.f, 0.f, 0.f, 0.f}};
            if (t > 0) {
                const unsigned tg = (unsigned)t;
                u64* Xp = Xl + (size_t)(t & 1) * 2048;
                u64 v[16];
                // own half (own-XCD L2, fast)
                int guard = 0;
                for (;;) {
#pragma unroll
                    for (int kk = 0; kk < 4; ++kk)
#pragma unroll
                        for (int p = 0; p < 4; ++p)
                            v[kk * 4 + p] = aload(Xp + (size_t)(kcOwn + kk) * 256 + rdB + p);
                    bool ok = true;
#pragma unroll
                    for (int i = 0; i < 16; ++i) ok &= ((unsigned)(v[i] >> 32) == tg);
                    if (ok) break;
                    if ((++guard & 127) == 0) {
                        if (guard > (1 << 18) || aflag(abortFlag)) { sflag(abortFlag); break; }
                    }
                }
                {
                    H8 afr[4];
#pragma unroll
                    for (int kk = 0; kk < 4; ++kk)
#pragma unroll
                        for (int p = 0; p < 4; ++p) afr[kk].u[p] = (unsigned)v[kk * 4 + p];
#pragma unroll
                    for (int kk = 0; kk < 4; ++kk)
#pragma unroll
                        for (int gam = 0; gam < 4; ++gam)
                            acc[gam] = __builtin_amdgcn_mfma_f32_16x16x32_f16(
                                afr[kk].v, bfr[gam][kcOwn + kk].v, acc[gam], 0, 0, 0);
                }
                // partner half
                guard = 0;
                for (;;) {
#pragma unroll
                    for (int kk = 0; kk < 4; ++kk)
#pragma unroll
                        for (int p = 0; p < 4; ++p)
                            v[kk * 4 + p] = aload(Xp + (size_t)(kcOth + kk) * 256 + rdB + p);
                    bool ok = true;
#pragma unroll
                    for (int i = 0; i < 16; ++i) ok &= ((unsigned)(v[i] >> 32) == tg);
                    if (ok) break;
                    if ((++guard & 127) == 0) {
                        if (guard > (1 << 18) || aflag(abortFlag)) { sflag(abortFlag); break; }
                    }
                }
                {
                    H8 afr[4];
#pragma unroll
                    for (int kk = 0; kk < 4; ++kk)
#pragma unroll
                        for (int p = 0; p < 4; ++p) afr[kk].u[p] = (unsigned)v[kk * 4 + p];
#pragma unroll
                    for (int kk = 0; kk < 4; ++kk)
#pragma unroll
                        for (int gam = 0; gam < 4; ++gam)
                            acc[gam] = __builtin_amdgcn_mfma_f32_16x16x32_f16(
                                afr[kk].v, bfr[gam][kcOth + kk].v, acc[gam], 0, 0, 0);
                }
            }

            // ---- verify GX (+R) tags (usually already satisfied) ----
            {
                int guard = 0;
                for (;;) {
                    bool ok = true;
#pragma unroll
                    for (int i = 0; i < 16; ++i) ok &= ((unsigned)(ga[i] >> 32) == tagT);
                    if (l > 0) {
#pragma unroll
                        for (int e = 0; e < 4; ++e) ok &= ((unsigned)(ar[e] >> 32) == tagT);
                    }
                    if (ok) break;
                    if (spinBail(guard, abortFlag)) break;
#pragma unroll
                    for (int gam = 0; gam < 4; ++gam)
#pragma unroll
                        for (int e = 0; e < 4; ++e) ga[gam * 4 + e] = aload(Gp + gam * 256 + e);
                    if (l > 0) {
#pragma unroll
                        for (int e = 0; e < 4; ++e) ar[e] = aload(Rp + e);
                    }
                }
            }
            if (l > 0) {
#pragma unroll
                for (int e = 0; e < 4; ++e) hin4[e] = __uint_as_float((unsigned)ar[e]);
            }

            // ---- gbuf exchange (parity double-buffer, one barrier) ----
            const int par = t & 1;
#pragma unroll
            for (int gam = 0; gam < 4; ++gam)
#pragma unroll
                for (int r = 0; r < 4; ++r)
                    gbuf[par][gam][quad * 4 + r][16 * wv + mm] = acc[gam][r];
            __syncthreads();

            // ---- gates: 4 state elems per thread ----
            float hv4[4];
#pragma unroll
            for (int e = 0; e < 4; ++e) {
                int dp = 4 * jj + e;
                float gi = gbuf[par][0][b][dp] + __uint_as_float((unsigned)ga[e]);
                float gf = gbuf[par][1][b][dp] + __uint_as_float((unsigned)ga[4 + e]);
                float gz = gbuf[par][2][b][dp] + __uint_as_float((unsigned)ga[8 + e]);
                float go = gbuf[par][3][b][dp] + __uint_as_float((unsigned)ga[12 + e]);
                float mn = fmaxf(gf + m_[e], gi);
                float ip = __expf(gi - mn);
                float fp = __expf(gf + m_[e] - mn);
                float e2z = __expf(2.f * gz);
                float th = 1.f - 2.f * __builtin_amdgcn_rcpf(e2z + 1.f);
                c_[e] = fp * c_[e] + ip * th;
                n_[e] = fp * n_[e] + ip;
                m_[e] = mn;
                float sg = __builtin_amdgcn_rcpf(1.f + __expf(-go));
                hv4[e] = sg * c_[e] * __builtin_amdgcn_rcpf(fmaxf(fabsf(n_[e]), 1.f));
            }

            // ---- publish X FIRST (partner's critical path) ----
            {
                u64* Xn = Xl + (size_t)((t + 1) & 1) * 2048 + xPub;
                astore(Xn, ((u64)tagT << 32) |
                               ((u64)f16b(hv4[0]) | ((u64)f16b(hv4[1]) << 16)));
                astore(Xn + 1, ((u64)tagT << 32) |
                                   ((u64)f16b(hv4[2]) | ((u64)f16b(hv4[3]) << 16)));
            }

            // ---- residual out ----
            float r0 = hin4[0] + hv4[0], r1 = hin4[1] + hv4[1];
            float r2 = hin4[2] + hv4[2], r3 = hin4[3] + hv4[3];
            if (l == 3) {
                *(float4*)(houtP + (size_t)t * DD) = float4{r0, r1, r2, r3};
            } else {
                if (t >= PRD) {
                    unsigned needT = (unsigned)(t - PRD);
                    if (!(consS >= needT + 2 && consH >= needT + 2)) {
                        int guard = 0;
                        for (;;) {
                            unsigned s0 = pload(consSP), s1 = pload(consSP + 1);
                            consS = s0 < s1 ? s0 : s1;
                            unsigned hmn = 0xffffffffu;
#pragma unroll
                            for (int q = 0; q < 8; ++q) {
                                unsigned p = pload(consHP + q);
                                hmn = p < hmn ? p : hmn;
                            }
                            consH = hmn;
                            if (consS >= needT + 2 && consH >= needT + 2) break;
                            if (spinBail(guard, abortFlag)) break;
                        }
                    }
                }
                u64* Rw = Rcur + (size_t)(t & (PRD - 1)) * 4096 + rOff;
                astore(Rw + 0, ((u64)tagT << 32) | (u64)__float_as_uint(r0));
                astore(Rw + 1, ((u64)tagT << 32) | (u64)__float_as_uint(r1));
                astore(Rw + 2, ((u64)tagT << 32) | (u64)__float_as_uint(r2));
                astore(Rw + 3, ((u64)tagT << 32) | (u64)__float_as_uint(r3));
            }
            if (tid == 0) pstore(myProg, tagT);  // after barrier => all GX/R reads done
        }
    } else {
        // ================= HELPER ROLE: weight-stationary gx GEMM =================
        const int idx = bid - 16;
        const int l = idx & 3, cg = (idx >> 2) & 3, j = (idx >> 4) & 1;
        const int wv = tid >> 6, lane = tid & 63;
        const int mm = lane & 15, quad = lane >> 4;
        const int b8 = tid >> 5, i8 = tid & 31;
        unsigned short (*hA)[264] = (unsigned short (*)[264])blob;

        // B-frags resident: 2 tiles per wave
        const int G0 = cg * 16 + 2 * wv, G1 = G0 + 1;
        H8 bfr0[8], bfr1[8];
        {
            const unsigned short* bp0 = Wxh + (size_t)(l * 64 + G0) * 4096 + (size_t)lane * 8;
            const unsigned short* bp1 = Wxh + (size_t)(l * 64 + G1) * 4096 + (size_t)lane * 8;
#pragma unroll
            for (int kc = 0; kc < 8; ++kc) {
                bfr0[kc].q = *(const uint4*)(bp0 + (size_t)kc * 512);
                bfr1[kc].q = *(const uint4*)(bp1 + (size_t)kc * 512);
            }
        }
        const float bg0 = bgp[(size_t)l * ND4 + G0 * 16 + mm];
        const float bg1 = bgp[(size_t)l * ND4 + G1 * 16 + mm];
        float lg[8], lb[8];
#pragma unroll
        for (int e = 0; e < 8; ++e) {
            lg[e] = lng[l * DD + i8 * 8 + e];
            lb[e] = lnb[l * DD + i8 * 8 + e];
        }

        const u64* Rin = Rbuf + (size_t)(l > 0 ? l - 1 : 0) * PRD * 4096;
        u64* GXl = GXbuf + (size_t)l * PGD * 16384;
        unsigned* myProg = prog + 8 + l * 8 + cg * 2 + j;
        const unsigned* sp = prog + l * 2;
        unsigned spC = 0;
        __syncthreads();

        for (int t = j; t < SS; t += 2) {
            const unsigned tagT = (unsigned)(t + 1);
            // ---- 1. acquire r[l-1][t] (or embed) : 8 consecutive elems ----
            float av[8];
            if (l == 0) {
                const float4* p = (const float4*)(hemb + ((size_t)b8 * SS + t) * DD + i8 * 8);
                float4 f0 = p[0], f1 = p[1];
                av[0] = f0.x; av[1] = f0.y; av[2] = f0.z; av[3] = f0.w;
                av[4] = f1.x; av[5] = f1.y; av[6] = f1.z; av[7] = f1.w;
            } else {
                const u64* Rp = Rin + (size_t)(t & (PRD - 1)) * 4096 + (size_t)b8 * 256 + i8 * 8;
                int guard = 0;
                for (;;) {
                    u64 vv[8];
#pragma unroll
                    for (int i = 0; i < 8; ++i) vv[i] = aload(Rp + i);
                    bool ok = true;
#pragma unroll
                    for (int i = 0; i < 8; ++i) ok &= ((unsigned)(vv[i] >> 32) == tagT);
                    if (ok) {
#pragma unroll
                        for (int i = 0; i < 8; ++i) av[i] = __uint_as_float((unsigned)vv[i]);
                        break;
                    }
                    if (spinBail(guard, abortFlag)) {
#pragma unroll
                        for (int i = 0; i < 8; ++i) av[i] = 0.f;
                        break;
                    }
                }
            }
            // ---- 2. LN stats (32-thread group per batch, within half-wave) ----
            float s = 0.f, ssq = 0.f;
#pragma unroll
            for (int i = 0; i < 8; ++i) { s += av[i]; ssq += av[i] * av[i]; }
#pragma unroll
            for (int msk = 1; msk < 32; msk <<= 1) {
                s += __shfl_xor(s, msk);
                ssq += __shfl_xor(ssq, msk);
            }
            float muv = s * (1.f / 256.f);
            float rsv = rsqrtf(fmaxf(ssq * (1.f / 256.f) - muv * muv, 0.f) + 1e-5f);
            // ---- 3. LN -> fp16 -> LDS ----
            {
                __align__(16) unsigned short ov[8];
#pragma unroll
                for (int i = 0; i < 8; ++i)
                    ov[i] = f16b((av[i] - muv) * rsv * lg[i] + lb[i]);
                *(uint4*)&hA[b8][i8 * 8] = *(uint4*)ov;
            }
            __syncthreads();
            // ---- 4. A-frags + MFMA (B resident in VGPRs) ----
            H8 A[8];
#pragma unroll
            for (int kc = 0; kc < 8; ++kc)
                A[kc].q = *(const uint4*)&hA[mm][kc * 32 + quad * 8];
            f32x4 a0 = {0.f, 0.f, 0.f, 0.f}, a1 = {0.f, 0.f, 0.f, 0.f};
#pragma unroll
            for (int kc = 0; kc < 8; ++kc) {
                a0 = __builtin_amdgcn_mfma_f32_16x16x32_f16(A[kc].v, bfr0[kc].v, a0, 0, 0, 0);
                a1 = __builtin_amdgcn_mfma_f32_16x16x32_f16(A[kc].v, bfr1[kc].v, a1, 0, 0, 0);
            }
            // ---- 5. slot-reuse gate (cached), publish GX ----
            if (t >= PGD) {
                unsigned need = (unsigned)(t - PGD) + 2;
                if (spC < need) {
                    int guard = 0;
                    for (;;) {
                        unsigned s0 = pload(sp), s1 = pload(sp + 1);
                        spC = s0 < s1 ? s0 : s1;
                        if (spC >= need) break;
                        if (spinBail(guard, abortFlag)) break;
                    }
                }
            }
            u64* Gq = GXl + (size_t)(t & (PGD - 1)) * 16384;
#pragma unroll
            for (int r = 0; r < 4; ++r) {
                size_t row = (size_t)(quad * 4 + r) * 1024;
                astore(Gq + row + G0 * 16 + mm,
                       ((u64)tagT << 32) | (u64)__float_as_uint(a0[r] + bg0));
                astore(Gq + row + G1 * 16 + mm,
                       ((u64)tagT << 32) | (u64)__float_as_uint(a1[r] + bg1));
            }
            __syncthreads();  // hA WAR for next token + all R reads complete
            if (tid == 0) pstore(myProg, tagT);
        }
    }
}

// ---------------------------------------------------------------------------
// final: out[b] = r3[b][S-1][:] . fc_W + fc_b
// ---------------------------------------------------------------------------
__global__ void final_kernel(const float* __restrict__ h, const float* __restrict__ fcW,
                             const float* __restrict__ fcb, float* __restrict__ out) {
    int b = blockIdx.x, lane = threadIdx.x;
    const float4 hv = *(const float4*)(h + ((size_t)b * SS + (SS - 1)) * DD + lane * 4);
    const float4 wv = *(const float4*)(fcW + lane * 4);
    float s = hv.x * wv.x + hv.y * wv.y + hv.z * wv.z + hv.w * wv.w;
#pragma unroll
    for (int off = 32; off; off >>= 1) s += __shfl_down(s, off);
    if (lane == 0) out[b] = s + fcb[0];
}

// ---------------------------------------------------------------------------
extern "C" void kernel_launch(void* const* d_in, const int* in_sizes, int n_in,
                              void* d_out, int out_size, void* d_ws, size_t ws_size,
                              hipStream_t stream) {
    const float* x   = (const float*)d_in[0];
    const float* tf  = (const float*)d_in[1];
    const float* inW = (const float*)d_in[2];
    const float* inb = (const float*)d_in[3];
    const float* lng = (const float*)d_in[4];
    const float* lnb = (const float*)d_in[5];
    const float* Wx  = (const float*)d_in[6];
    const float* Wh  = (const float*)d_in[7];
    const float* bg  = (const float*)d_in[8];
    const float* fcW = (const float*)d_in[9];
    const float* fcb = (const float*)d_in[10];
    float* out = (float*)d_out;

    const size_t nTok = (size_t)BB * SS;
    float* hemb = (float*)d_ws;                                   // 8,388,608 f
    float* hout = hemb + nTok * DD;                               // 8,388,608 f
    unsigned short* Wxh = (unsigned short*)(hout + nTok * DD);    // 1,048,576 us
    unsigned short* Whh = Wxh + 1048576;                          // 1,048,576 us
    u64* Xbuf = (u64*)(Whh + 1048576);                            // 4*4096
    u64* Rbuf = Xbuf + 4 * 4096;                                  // 3*PRD*4096
    u64* GXbuf = Rbuf + 3 * PRD * 4096;                           // 4*PGD*16384
    unsigned* prog = (unsigned*)(GXbuf + 4 * PGD * 16384);        // 40 u32
    int* abortFlag = (int*)(prog + 40);

    const size_t needed = (size_t)((char*)(abortFlag + 1) - (char*)d_ws);
    if (ws_size < needed) return;  // fail visibly instead of corrupting

    hipMemsetAsync(prog, 0, 40 * sizeof(unsigned) + sizeof(int), stream);
    // X/R/GX need no init: 0xAA poison never matches a tag in [1,2048]

    embed_kernel<<<nTok, DD, 0, stream>>>(x, tf, inW, inb, hemb);
    wprep_kernel<<<256, 64, 0, stream>>>(Wx, Wxh);
    wprep_kernel<<<256, 64, 0, stream>>>(Wh, Whh);
    mega_kernel<<<48, 512, 0, stream>>>(hemb, Whh, Wxh, lng, lnb, bg, hout,
                                        Xbuf, Rbuf, GXbuf, prog, abortFlag);
    final_kernel<<<BB, 64, 0, stream>>>(hout, fcW, fcb, out);
    (void)in_sizes; (void)n_in; (void)out_size;
}

// Round 7
// 15290.442 us; speedup vs baseline: 2.1676x; 2.1676x over previous
//
#include <hip/hip_runtime.h>

// Problem constants
#define BB 16
#define SS 2048
#define DD 256
#define ND4 1024   // 4*D
#define PRD 16     // R-buffer slot depth
#define PGD 8      // GX-buffer slot depth

typedef __attribute__((ext_vector_type(8))) _Float16 half8;
typedef __attribute__((ext_vector_type(4))) float f32x4;
typedef unsigned long long u64;
union H8 { half8 v; unsigned u[4]; uint4 q; };
union F4 { f32x4 v; float f[4]; };

__device__ __forceinline__ u64 aload(const u64* p) {
    return __hip_atomic_load(p, __ATOMIC_RELAXED, __HIP_MEMORY_SCOPE_AGENT);
}
__device__ __forceinline__ void astore(u64* p, u64 v) {
    __hip_atomic_store(p, v, __ATOMIC_RELAXED, __HIP_MEMORY_SCOPE_AGENT);
}
__device__ __forceinline__ unsigned pload(const unsigned* p) {
    return __hip_atomic_load(p, __ATOMIC_RELAXED, __HIP_MEMORY_SCOPE_AGENT);
}
__device__ __forceinline__ void pstore(unsigned* p, unsigned v) {
    __hip_atomic_store(p, v, __ATOMIC_RELAXED, __HIP_MEMORY_SCOPE_AGENT);
}
__device__ __forceinline__ int aflag(int* p) {
    return __hip_atomic_load(p, __ATOMIC_RELAXED, __HIP_MEMORY_SCOPE_AGENT);
}
__device__ __forceinline__ void sflag(int* p) {
    __hip_atomic_store(p, 1, __ATOMIC_RELAXED, __HIP_MEMORY_SCOPE_AGENT);
}
__device__ __forceinline__ unsigned short f16b(float x) {
    union { _Float16 h; unsigned short u; } c; c.h = (_Float16)x; return c.u;
}
__device__ __forceinline__ bool spinBail(int& guard, int* af) {
    if ((++guard & 63) == 0) {
        __builtin_amdgcn_s_sleep(1);
        if (guard > (1 << 18) || aflag(af)) { sflag(af); return true; }
    }
    return false;
}

// ---------------------------------------------------------------------------
// embed: h0 = [x | tf] @ in_W + in_b
// ---------------------------------------------------------------------------
__global__ void embed_kernel(const float* __restrict__ x, const float* __restrict__ tf,
                             const float* __restrict__ inW, const float* __restrict__ inb,
                             float* __restrict__ h) {
    int tok = blockIdx.x, d = threadIdx.x;
    float xv = x[tok];
    float acc = inb[d] + xv * inW[d];
#pragma unroll
    for (int c = 0; c < 6; ++c)
        acc = fmaf(tf[tok * 6 + c], inW[(c + 1) * DD + d], acc);
    h[(size_t)tok * DD + d] = acc;
}

// ---------------------------------------------------------------------------
// W[4][256][1024] fp32 -> fp16 B-fragment order (Wx and Wh):
// out[((l*64+G)*8+kc)*64 + lane][8]; elem i = W[l][kc*32+quad*8+i][G*16+mm]
// ---------------------------------------------------------------------------
__global__ void wprep_kernel(const float* __restrict__ W, unsigned short* __restrict__ Wo) {
    int l = blockIdx.x >> 6, G = blockIdx.x & 63;
    int lane = threadIdx.x, quad = lane >> 4, mm = lane & 15;
    const float* Wl = W + (size_t)l * DD * ND4;
    unsigned short* o = Wo + (size_t)blockIdx.x * 4096;
#pragma unroll
    for (int kc = 0; kc < 8; ++kc) {
        __align__(16) unsigned short tmp[8];
#pragma unroll
        for (int i = 0; i < 8; ++i)
            tmp[i] = f16b(Wl[(size_t)(kc * 32 + quad * 8 + i) * ND4 + G * 16 + mm]);
        *(uint4*)(o + ((size_t)kc * 64 + lane) * 8) = *(uint4*)tmp;
    }
}

// ---------------------------------------------------------------------------
// Mega kernel, ring-of-2 (R6 topology, R7 fixes):
//  - bfrOwn/bfrOth: compile-time register indices ONLY (R6's runtime-indexed
//    bfr[kcOwn+kk] scratch-spilled the B-frags -> VGPR_Count 84, 4x slowdown)
//  - own-half h exchanged through LDS mirror (hX), only partner half polled
//  - gate reads as float4; two barriers/step
// WGs: bid 0..3 scan(l,s=0), 8..11 scan(l,s=1) [bid pairing for same-XCD],
//      4..7,12..15 idle, 16..47 helper (weight-stationary gx GEMM).
// ---------------------------------------------------------------------------
__global__ __launch_bounds__(512, 1) void mega_kernel(
    const float* __restrict__ hemb, const unsigned short* __restrict__ Whh,
    const unsigned short* __restrict__ Wxh,
    const float* __restrict__ lng, const float* __restrict__ lnb,
    const float* __restrict__ bgp, float* __restrict__ hout,
    u64* __restrict__ Xbuf, u64* __restrict__ Rbuf, u64* __restrict__ GXbuf,
    unsigned* __restrict__ prog, int* __restrict__ abortFlag) {
    __shared__ __align__(16) char blob[75776];  // gbuf 67584 + hX 8192
    const int bid = blockIdx.x;
    const int tid = threadIdx.x;

    if (bid < 16) {
        if ((bid & 7) >= 4) return;  // idle pads (XCD-pairing layout)
        // ================= SCAN ROLE =================
        const int l = bid & 3, s = bid >> 3;
        const int wv = tid >> 6, lane = tid & 63;
        const int mm = lane & 15, quad = lane >> 4;
        const int b = tid >> 5, jj = tid & 31;
        const int dbase = 128 * s + 4 * jj;
        float (*gbuf)[4][16][132] = (float (*)[4][16][132])blob;
        unsigned* hX = (unsigned*)(blob + 67584);  // [2][1024] fp16-pair mirror

        // B-frags, constant register indexing (own chunks then partner chunks)
        H8 bfrOwn[4][4], bfrOth[4][4];
        {
            const int kcO = 4 * s, kcT = 4 - 4 * s;
#pragma unroll
            for (int gam = 0; gam < 4; ++gam) {
                const unsigned short* bp =
                    Whh + (size_t)(l * 64 + gam * 16 + 8 * s + wv) * 4096 + (size_t)lane * 8;
#pragma unroll
                for (int kk = 0; kk < 4; ++kk) {
                    bfrOwn[gam][kk].q = *(const uint4*)(bp + (size_t)(kcO + kk) * 512);
                    bfrOth[gam][kk].q = *(const uint4*)(bp + (size_t)(kcT + kk) * 512);
                }
            }
        }

        float c_[4] = {0.f, 0.f, 0.f, 0.f}, n_[4] = {0.f, 0.f, 0.f, 0.f},
              m_[4] = {0.f, 0.f, 0.f, 0.f};

        u64* Xl = Xbuf + (size_t)l * 4096;
        const u64* Rprev = Rbuf + (size_t)(l > 0 ? l - 1 : 0) * PRD * 4096;
        u64* Rcur = Rbuf + (size_t)(l < 3 ? l : 0) * PRD * 4096;
        u64* GXl = GXbuf + (size_t)l * PGD * 16384;

        // publisher slot: chunk=dbase>>5, quad-part=(dbase>>3)&3, pair=(dbase&7)>>1
        const int lChunk = jj >> 3, lQuad = (jj >> 1) & 3, pP = (jj & 1) * 2;
        const size_t xPub = (size_t)(4 * s + lChunk) * 256 + (size_t)lQuad * 64 +
                            (size_t)b * 4 + pP;
        const unsigned ldsPub = (unsigned)(lChunk * 256 + lQuad * 64 + b * 4 + pP);
        const size_t rdB = (size_t)quad * 64 + (size_t)mm * 4;
        const int kcOth = 4 - 4 * s;

        const size_t gxOff = (size_t)b * 1024 + dbase;
        const size_t rOff = (size_t)b * 256 + dbase;
        const float* hembP = hemb + (size_t)b * SS * DD + dbase;
        float* houtP = hout + (size_t)b * SS * DD + dbase;
        const unsigned* consSP = prog + (l + 1) * 2;
        const unsigned* consHP = prog + 8 + (l + 1) * 8;
        unsigned consS = 0, consH = 0;
        unsigned* myProg = prog + l * 2 + s;
        __syncthreads();

        for (int t = 0; t < SS; ++t) {
            const unsigned tagT = (unsigned)(t + 1);
            // ---- A. early-issue GX (+R/embed) loads ----
            const u64* Gp = GXl + (size_t)(t & (PGD - 1)) * 16384 + gxOff;
            const u64* Rp = Rprev + (size_t)(t & (PRD - 1)) * 4096 + rOff;
            u64 ga[16];
#pragma unroll
            for (int gam = 0; gam < 4; ++gam)
#pragma unroll
                for (int e = 0; e < 4; ++e) ga[gam * 4 + e] = aload(Gp + gam * 256 + e);
            u64 ar[4] = {0, 0, 0, 0};
            float hin4[4] = {0.f, 0.f, 0.f, 0.f};
            if (l > 0) {
#pragma unroll
                for (int e = 0; e < 4; ++e) ar[e] = aload(Rp + e);
            } else {
                float4 hv = *(const float4*)(hembP + (size_t)t * DD);
                hin4[0] = hv.x; hin4[1] = hv.y; hin4[2] = hv.z; hin4[3] = hv.w;
            }

            f32x4 acc[4] = {{0.f, 0.f, 0.f, 0.f}, {0.f, 0.f, 0.f, 0.f},
                            {0.f, 0.f, 0.f, 0.f}, {0.f, 0.f, 0.f, 0.f}};
            // ---- B. own half from LDS mirror (barrier-guaranteed, no poll) ----
            if (t > 0) {
                const unsigned* hXp = hX + (t & 1) * 1024;
                H8 afr[4];
#pragma unroll
                for (int kk = 0; kk < 4; ++kk)
#pragma unroll
                    for (int p = 0; p < 4; ++p)
                        afr[kk].u[p] = hXp[kk * 256 + (unsigned)rdB + p];
#pragma unroll
                for (int kk = 0; kk < 4; ++kk)
#pragma unroll
                    for (int gam = 0; gam < 4; ++gam)
                        acc[gam] = __builtin_amdgcn_mfma_f32_16x16x32_f16(
                            afr[kk].v, bfrOwn[gam][kk].v, acc[gam], 0, 0, 0);
            }

            // ---- C. verify GX/R tags, convert to floats (frees u64 regs) ----
            float gxv[16];
            {
                int guard = 0;
                for (;;) {
                    bool ok = true;
#pragma unroll
                    for (int i = 0; i < 16; ++i) ok &= ((unsigned)(ga[i] >> 32) == tagT);
                    if (l > 0) {
#pragma unroll
                        for (int e = 0; e < 4; ++e) ok &= ((unsigned)(ar[e] >> 32) == tagT);
                    }
                    if (ok) break;
                    if (spinBail(guard, abortFlag)) break;
#pragma unroll
                    for (int gam = 0; gam < 4; ++gam)
#pragma unroll
                        for (int e = 0; e < 4; ++e) ga[gam * 4 + e] = aload(Gp + gam * 256 + e);
                    if (l > 0) {
#pragma unroll
                        for (int e = 0; e < 4; ++e) ar[e] = aload(Rp + e);
                    }
                }
#pragma unroll
                for (int i = 0; i < 16; ++i) gxv[i] = __uint_as_float((unsigned)ga[i]);
                if (l > 0) {
#pragma unroll
                    for (int e = 0; e < 4; ++e) hin4[e] = __uint_as_float((unsigned)ar[e]);
                }
            }

            // ---- D. partner half: poll 16 atoms ----
            if (t > 0) {
                const unsigned tg = (unsigned)t;
                u64* Xp = Xl + (size_t)(t & 1) * 2048;
                u64 v[16];
                int guard = 0;
                for (;;) {
#pragma unroll
                    for (int kk = 0; kk < 4; ++kk)
#pragma unroll
                        for (int p = 0; p < 4; ++p)
                            v[kk * 4 + p] = aload(Xp + (size_t)(kcOth + kk) * 256 + rdB + p);
                    bool ok = true;
#pragma unroll
                    for (int i = 0; i < 16; ++i) ok &= ((unsigned)(v[i] >> 32) == tg);
                    if (ok) break;
                    if ((++guard & 127) == 0) {
                        if (guard > (1 << 18) || aflag(abortFlag)) { sflag(abortFlag); break; }
                    }
                }
                H8 afr[4];
#pragma unroll
                for (int kk = 0; kk < 4; ++kk)
#pragma unroll
                    for (int p = 0; p < 4; ++p) afr[kk].u[p] = (unsigned)v[kk * 4 + p];
#pragma unroll
                for (int kk = 0; kk < 4; ++kk)
#pragma unroll
                    for (int gam = 0; gam < 4; ++gam)
                        acc[gam] = __builtin_amdgcn_mfma_f32_16x16x32_f16(
                            afr[kk].v, bfrOth[gam][kk].v, acc[gam], 0, 0, 0);
            }

            // ---- E. gbuf exchange, barrier 1 ----
            const int par = t & 1;
#pragma unroll
            for (int gam = 0; gam < 4; ++gam)
#pragma unroll
                for (int r = 0; r < 4; ++r)
                    gbuf[par][gam][quad * 4 + r][16 * wv + mm] = acc[gam][r];
            __syncthreads();

            // ---- F. gates (float4 gbuf reads) ----
            F4 gq[4];
#pragma unroll
            for (int gam = 0; gam < 4; ++gam)
                gq[gam].v = *(const f32x4*)&gbuf[par][gam][b][4 * jj];
            float hv4[4];
#pragma unroll
            for (int e = 0; e < 4; ++e) {
                float gi = gq[0].f[e] + gxv[e];
                float gf = gq[1].f[e] + gxv[4 + e];
                float gz = gq[2].f[e] + gxv[8 + e];
                float go = gq[3].f[e] + gxv[12 + e];
                float mn = fmaxf(gf + m_[e], gi);
                float ip = __expf(gi - mn);
                float fp = __expf(gf + m_[e] - mn);
                float e2z = __expf(2.f * gz);
                float th = 1.f - 2.f * __builtin_amdgcn_rcpf(e2z + 1.f);
                c_[e] = fp * c_[e] + ip * th;
                n_[e] = fp * n_[e] + ip;
                m_[e] = mn;
                float sg = __builtin_amdgcn_rcpf(1.f + __expf(-go));
                hv4[e] = sg * c_[e] * __builtin_amdgcn_rcpf(fmaxf(fabsf(n_[e]), 1.f));
            }
            unsigned pay0 = (unsigned)f16b(hv4[0]) | ((unsigned)f16b(hv4[1]) << 16);
            unsigned pay1 = (unsigned)f16b(hv4[2]) | ((unsigned)f16b(hv4[3]) << 16);

            // ---- G. publish partner X FIRST, then LDS mirror ----
            {
                u64* Xn = Xl + (size_t)((t + 1) & 1) * 2048 + xPub;
                astore(Xn, ((u64)tagT << 32) | pay0);
                astore(Xn + 1, ((u64)tagT << 32) | pay1);
                unsigned* hXn = hX + ((t + 1) & 1) * 1024 + ldsPub;
                hXn[0] = pay0;
                hXn[1] = pay1;
            }

            // ---- H. residual out ----
            float r0 = hin4[0] + hv4[0], r1 = hin4[1] + hv4[1];
            float r2 = hin4[2] + hv4[2], r3 = hin4[3] + hv4[3];
            if (l == 3) {
                *(float4*)(houtP + (size_t)t * DD) = float4{r0, r1, r2, r3};
            } else {
                if (t >= PRD) {
                    unsigned needT = (unsigned)(t - PRD);
                    if (!(consS >= needT + 2 && consH >= needT + 2)) {
                        int guard = 0;
                        for (;;) {
                            unsigned s0 = pload(consSP), s1 = pload(consSP + 1);
                            consS = s0 < s1 ? s0 : s1;
                            unsigned hmn = 0xffffffffu;
#pragma unroll
                            for (int q = 0; q < 8; ++q) {
                                unsigned p = pload(consHP + q);
                                hmn = p < hmn ? p : hmn;
                            }
                            consH = hmn;
                            if (consS >= needT + 2 && consH >= needT + 2) break;
                            if (spinBail(guard, abortFlag)) break;
                        }
                    }
                }
                u64* Rw = Rcur + (size_t)(t & (PRD - 1)) * 4096 + rOff;
                astore(Rw + 0, ((u64)tagT << 32) | (u64)__float_as_uint(r0));
                astore(Rw + 1, ((u64)tagT << 32) | (u64)__float_as_uint(r1));
                astore(Rw + 2, ((u64)tagT << 32) | (u64)__float_as_uint(r2));
                astore(Rw + 3, ((u64)tagT << 32) | (u64)__float_as_uint(r3));
            }
            __syncthreads();  // barrier 2: hX mirror ready; GX/R reads all done
            if (tid == 0) pstore(myProg, tagT);
        }
    } else {
        // ================= HELPER ROLE: weight-stationary gx GEMM =================
        const int idx = bid - 16;
        const int l = idx & 3, cg = (idx >> 2) & 3, j = (idx >> 4) & 1;
        const int wv = tid >> 6, lane = tid & 63;
        const int mm = lane & 15, quad = lane >> 4;
        const int b8 = tid >> 5, i8 = tid & 31;
        unsigned short (*hA)[264] = (unsigned short (*)[264])blob;

        const int G0 = cg * 16 + 2 * wv, G1 = G0 + 1;
        H8 bfr0[8], bfr1[8];
        {
            const unsigned short* bp0 = Wxh + (size_t)(l * 64 + G0) * 4096 + (size_t)lane * 8;
            const unsigned short* bp1 = Wxh + (size_t)(l * 64 + G1) * 4096 + (size_t)lane * 8;
#pragma unroll
            for (int kc = 0; kc < 8; ++kc) {
                bfr0[kc].q = *(const uint4*)(bp0 + (size_t)kc * 512);
                bfr1[kc].q = *(const uint4*)(bp1 + (size_t)kc * 512);
            }
        }
        const float bg0 = bgp[(size_t)l * ND4 + G0 * 16 + mm];
        const float bg1 = bgp[(size_t)l * ND4 + G1 * 16 + mm];
        float lg[8], lb[8];
#pragma unroll
        for (int e = 0; e < 8; ++e) {
            lg[e] = lng[l * DD + i8 * 8 + e];
            lb[e] = lnb[l * DD + i8 * 8 + e];
        }

        const u64* Rin = Rbuf + (size_t)(l > 0 ? l - 1 : 0) * PRD * 4096;
        u64* GXl = GXbuf + (size_t)l * PGD * 16384;
        unsigned* myProg = prog + 8 + l * 8 + cg * 2 + j;
        const unsigned* sp = prog + l * 2;
        unsigned spC = 0;
        __syncthreads();

        for (int t = j; t < SS; t += 2) {
            const unsigned tagT = (unsigned)(t + 1);
            // ---- 1. acquire r[l-1][t] (or embed) ----
            float av[8];
            if (l == 0) {
                const float4* p = (const float4*)(hemb + ((size_t)b8 * SS + t) * DD + i8 * 8);
                float4 f0 = p[0], f1 = p[1];
                av[0] = f0.x; av[1] = f0.y; av[2] = f0.z; av[3] = f0.w;
                av[4] = f1.x; av[5] = f1.y; av[6] = f1.z; av[7] = f1.w;
            } else {
                const u64* Rp = Rin + (size_t)(t & (PRD - 1)) * 4096 + (size_t)b8 * 256 + i8 * 8;
                int guard = 0;
                for (;;) {
                    u64 vv[8];
#pragma unroll
                    for (int i = 0; i < 8; ++i) vv[i] = aload(Rp + i);
                    bool ok = true;
#pragma unroll
                    for (int i = 0; i < 8; ++i) ok &= ((unsigned)(vv[i] >> 32) == tagT);
                    if (ok) {
#pragma unroll
                        for (int i = 0; i < 8; ++i) av[i] = __uint_as_float((unsigned)vv[i]);
                        break;
                    }
                    if (spinBail(guard, abortFlag)) {
#pragma unroll
                        for (int i = 0; i < 8; ++i) av[i] = 0.f;
                        break;
                    }
                }
            }
            // ---- 2. LN stats ----
            float s = 0.f, ssq = 0.f;
#pragma unroll
            for (int i = 0; i < 8; ++i) { s += av[i]; ssq += av[i] * av[i]; }
#pragma unroll
            for (int msk = 1; msk < 32; msk <<= 1) {
                s += __shfl_xor(s, msk);
                ssq += __shfl_xor(ssq, msk);
            }
            float muv = s * (1.f / 256.f);
            float rsv = rsqrtf(fmaxf(ssq * (1.f / 256.f) - muv * muv, 0.f) + 1e-5f);
            // ---- 3. LN -> fp16 -> LDS ----
            {
                __align__(16) unsigned short ov[8];
#pragma unroll
                for (int i = 0; i < 8; ++i)
                    ov[i] = f16b((av[i] - muv) * rsv * lg[i] + lb[i]);
                *(uint4*)&hA[b8][i8 * 8] = *(uint4*)ov;
            }
            __syncthreads();
            // ---- 4. A-frags + MFMA (B resident) ----
            H8 A[8];
#pragma unroll
            for (int kc = 0; kc < 8; ++kc)
                A[kc].q = *(const uint4*)&hA[mm][kc * 32 + quad * 8];
            f32x4 a0 = {0.f, 0.f, 0.f, 0.f}, a1 = {0.f, 0.f, 0.f, 0.f};
#pragma unroll
            for (int kc = 0; kc < 8; ++kc) {
                a0 = __builtin_amdgcn_mfma_f32_16x16x32_f16(A[kc].v, bfr0[kc].v, a0, 0, 0, 0);
                a1 = __builtin_amdgcn_mfma_f32_16x16x32_f16(A[kc].v, bfr1[kc].v, a1, 0, 0, 0);
            }
            // ---- 5. slot gate (cached), publish GX ----
            if (t >= PGD) {
                unsigned need = (unsigned)(t - PGD) + 2;
                if (spC < need) {
                    int guard = 0;
                    for (;;) {
                        unsigned s0 = pload(sp), s1 = pload(sp + 1);
                        spC = s0 < s1 ? s0 : s1;
                        if (spC >= need) break;
                        if (spinBail(guard, abortFlag)) break;
                    }
                }
            }
            u64* Gq = GXl + (size_t)(t & (PGD - 1)) * 16384;
#pragma unroll
            for (int r = 0; r < 4; ++r) {
                size_t row = (size_t)(quad * 4 + r) * 1024;
                astore(Gq + row + G0 * 16 + mm,
                       ((u64)tagT << 32) | (u64)__float_as_uint(a0[r] + bg0));
                astore(Gq + row + G1 * 16 + mm,
                       ((u64)tagT << 32) | (u64)__float_as_uint(a1[r] + bg1));
            }
            __syncthreads();  // hA WAR + all R reads complete
            if (tid == 0) pstore(myProg, tagT);
        }
    }
}

// ---------------------------------------------------------------------------
// final: out[b] = r3[b][S-1][:] . fc_W + fc_b
// ---------------------------------------------------------------------------
__global__ void final_kernel(const float* __restrict__ h, const float* __restrict__ fcW,
                             const float* __restrict__ fcb, float* __restrict__ out) {
    int b = blockIdx.x, lane = threadIdx.x;
    const float4 hv = *(const float4*)(h + ((size_t)b * SS + (SS - 1)) * DD + lane * 4);
    const float4 wv = *(const float4*)(fcW + lane * 4);
    float s = hv.x * wv.x + hv.y * wv.y + hv.z * wv.z + hv.w * wv.w;
#pragma unroll
    for (int off = 32; off; off >>= 1) s += __shfl_down(s, off);
    if (lane == 0) out[b] = s + fcb[0];
}

// ---------------------------------------------------------------------------
extern "C" void kernel_launch(void* const* d_in, const int* in_sizes, int n_in,
                              void* d_out, int out_size, void* d_ws, size_t ws_size,
                              hipStream_t stream) {
    const float* x   = (const float*)d_in[0];
    const float* tf  = (const float*)d_in[1];
    const float* inW = (const float*)d_in[2];
    const float* inb = (const float*)d_in[3];
    const float* lng = (const float*)d_in[4];
    const float* lnb = (const float*)d_in[5];
    const float* Wx  = (const float*)d_in[6];
    const float* Wh  = (const float*)d_in[7];
    const float* bg  = (const float*)d_in[8];
    const float* fcW = (const float*)d_in[9];
    const float* fcb = (const float*)d_in[10];
    float* out = (float*)d_out;

    const size_t nTok = (size_t)BB * SS;
    float* hemb = (float*)d_ws;
    float* hout = hemb + nTok * DD;
    unsigned short* Wxh = (unsigned short*)(hout + nTok * DD);
    unsigned short* Whh = Wxh + 1048576;
    u64* Xbuf = (u64*)(Whh + 1048576);
    u64* Rbuf = Xbuf + 4 * 4096;
    u64* GXbuf = Rbuf + 3 * PRD * 4096;
    unsigned* prog = (unsigned*)(GXbuf + 4 * PGD * 16384);
    int* abortFlag = (int*)(prog + 40);

    const size_t needed = (size_t)((char*)(abortFlag + 1) - (char*)d_ws);
    if (ws_size < needed) return;

    hipMemsetAsync(prog, 0, 40 * sizeof(unsigned) + sizeof(int), stream);
    // X/R/GX need no init: 0xAA poison never matches a tag in [1,2048]

    embed_kernel<<<nTok, DD, 0, stream>>>(x, tf, inW, inb, hemb);
    wprep_kernel<<<256, 64, 0, stream>>>(Wx, Wxh);
    wprep_kernel<<<256, 64, 0, stream>>>(Wh, Whh);
    mega_kernel<<<48, 512, 0, stream>>>(hemb, Whh, Wxh, lng, lnb, bg, hout,
                                        Xbuf, Rbuf, GXbuf, prog, abortFlag);
    final_kernel<<<BB, 64, 0, stream>>>(hout, fcW, fcb, out);
    (void)in_sizes; (void)n_in; (void)out_size;
}

// Round 8
// 9390.977 us; speedup vs baseline: 3.5293x; 1.6282x over previous
//
#include <hip/hip_runtime.h>

// Problem constants
#define BB 16
#define SS 2048
#define DD 256
#define ND4 1024   // 4*D
#define PRD 16     // R-stream slot depth

typedef __attribute__((ext_vector_type(8))) _Float16 half8;
typedef __attribute__((ext_vector_type(4))) float f32x4;
typedef unsigned long long u64;
union H8 { half8 v; unsigned u[4]; uint4 q; };

__device__ __forceinline__ u64 aload(const u64* p) {
    return __hip_atomic_load(p, __ATOMIC_RELAXED, __HIP_MEMORY_SCOPE_AGENT);
}
__device__ __forceinline__ void astore(u64* p, u64 v) {
    __hip_atomic_store(p, v, __ATOMIC_RELAXED, __HIP_MEMORY_SCOPE_AGENT);
}
__device__ __forceinline__ unsigned pload(const unsigned* p) {
    return __hip_atomic_load(p, __ATOMIC_RELAXED, __HIP_MEMORY_SCOPE_AGENT);
}
__device__ __forceinline__ void pstore(unsigned* p, unsigned v) {
    __hip_atomic_store(p, v, __ATOMIC_RELAXED, __HIP_MEMORY_SCOPE_AGENT);
}
__device__ __forceinline__ int aflag(int* p) {
    return __hip_atomic_load(p, __ATOMIC_RELAXED, __HIP_MEMORY_SCOPE_AGENT);
}
__device__ __forceinline__ void sflag(int* p) {
    __hip_atomic_store(p, 1, __ATOMIC_RELAXED, __HIP_MEMORY_SCOPE_AGENT);
}
__device__ __forceinline__ unsigned short f16b(float x) {
    union { _Float16 h; unsigned short u; } c; c.h = (_Float16)x; return c.u;
}
__device__ __forceinline__ bool spinBail(int& guard, int* af) {
    if ((++guard & 63) == 0) {
        __builtin_amdgcn_s_sleep(1);
        if (guard > (1 << 18) || aflag(af)) { sflag(af); return true; }
    }
    return false;
}

// ---------------------------------------------------------------------------
// embed: h0 = [x | tf] @ in_W + in_b
// ---------------------------------------------------------------------------
__global__ void embed_kernel(const float* __restrict__ x, const float* __restrict__ tf,
                             const float* __restrict__ inW, const float* __restrict__ inb,
                             float* __restrict__ h) {
    int tok = blockIdx.x, d = threadIdx.x;
    float xv = x[tok];
    float acc = inb[d] + xv * inW[d];
#pragma unroll
    for (int c = 0; c < 6; ++c)
        acc = fmaf(tf[tok * 6 + c], inW[(c + 1) * DD + d], acc);
    h[(size_t)tok * DD + d] = acc;
}

// ---------------------------------------------------------------------------
// Wh -> fp16 B-fragment order (layout validated R4/R7):
// out[(l*64+G)*4096 + kc*512 + lane*8 + i] = W[l][kc*32+quad*8+i][G*16+mm]
// ---------------------------------------------------------------------------
__global__ void wprep_wh_kernel(const float* __restrict__ W, unsigned short* __restrict__ Wo) {
    int l = blockIdx.x >> 6, G = blockIdx.x & 63;
    int lane = threadIdx.x, quad = lane >> 4, mm = lane & 15;
    const float* Wl = W + (size_t)l * DD * ND4;
    unsigned short* o = Wo + (size_t)blockIdx.x * 4096;
#pragma unroll
    for (int kc = 0; kc < 8; ++kc) {
        __align__(16) unsigned short tmp[8];
#pragma unroll
        for (int i = 0; i < 8; ++i)
            tmp[i] = f16b(Wl[(size_t)(kc * 32 + quad * 8 + i) * ND4 + G * 16 + mm]);
        *(uint4*)(o + ((size_t)kc * 64 + lane) * 8) = *(uint4*)tmp;
    }
}

// ---------------------------------------------------------------------------
// Wx' = diag(ln_g) @ Wx  -> fp16 B-fragment order (gamma folded into weights)
// ---------------------------------------------------------------------------
__global__ void wprep_wx_kernel(const float* __restrict__ W, const float* __restrict__ lng,
                                unsigned short* __restrict__ Wo) {
    int l = blockIdx.x >> 6, G = blockIdx.x & 63;
    int lane = threadIdx.x, quad = lane >> 4, mm = lane & 15;
    const float* Wl = W + (size_t)l * DD * ND4;
    const float* gl = lng + l * DD;
    unsigned short* o = Wo + (size_t)blockIdx.x * 4096;
#pragma unroll
    for (int kc = 0; kc < 8; ++kc) {
        __align__(16) unsigned short tmp[8];
#pragma unroll
        for (int i = 0; i < 8; ++i) {
            int k = kc * 32 + quad * 8 + i;
            tmp[i] = f16b(gl[k] * Wl[(size_t)k * ND4 + G * 16 + mm]);
        }
        *(uint4*)(o + ((size_t)kc * 64 + lane) * 8) = *(uint4*)tmp;
    }
}

// ---------------------------------------------------------------------------
// bg' = bg + ln_b @ Wx  (beta folded into the gate bias; fp32 exact)
// ---------------------------------------------------------------------------
__global__ void bgprep_kernel(const float* __restrict__ bg, const float* __restrict__ lnb,
                              const float* __restrict__ Wx, float* __restrict__ bgp2) {
    int idx = blockIdx.x * 256 + threadIdx.x;   // 0..4095
    int l = idx >> 10, col = idx & 1023;
    const float* Wl = Wx + (size_t)l * DD * ND4;
    const float* bl = lnb + l * DD;
    float acc = bg[idx];
    for (int d = 0; d < DD; ++d) acc = fmaf(bl[d], Wl[(size_t)d * ND4 + col], acc);
    bgp2[idx] = acc;
}

// ---------------------------------------------------------------------------
// Mega kernel, helper-free: 64 WGs x 256 thr, WG = (l=bid>>4, g=bid&15).
// Each scan WG computes BOTH GEMM contributions itself:
//   acc = z(t) @ Wx'[cols]  +  h_s(t-1) @ Wh[cols]      (+ bg' at gate time)
// z built consumer-side: r from layer l-1's Rn stream (fp16 pairs, A-frag
// order, same proven layout as X), stats via lane-sum + quad-shfl, gamma/beta
// pre-folded into Wx'/bg'. hin via fp32 Rf side-channel (residual exact).
// GX buffer and helper WGs DELETED (was 1.07 GB/step-stream + extra hop).
// All R1-R7 lessons kept: tagged u64 atoms (fence-free), line-private
// publish regions, parity/depth slot reuse with prog gates, abort bailouts,
// compile-time-only register-array indexing (R6/R7 spill lesson).
// ---------------------------------------------------------------------------
__global__ __launch_bounds__(256, 1) void mega_kernel(
    const float* __restrict__ hemb, const unsigned short* __restrict__ Whh,
    const unsigned short* __restrict__ Wxh, const float* __restrict__ bgp2,
    float* __restrict__ hout,
    u64* __restrict__ Xbuf, u64* __restrict__ Rn, u64* __restrict__ Rf,
    unsigned* __restrict__ prog, int* __restrict__ abortFlag) {
    __shared__ float gbuf[2][4][16][18];   // stride 18 -> 2-way max (free)
    const int bid = blockIdx.x;
    const int tid = threadIdx.x;
    const int l = bid >> 4, g = bid & 15;
    const int w = tid >> 6, lane = tid & 63;
    const int mm = lane & 15, quad = lane >> 4;
    const int sb = tid >> 4, sd = tid & 15;
    const int dglob = g * 16 + sd;

    // B fragments (tile G = w*16+g), compile-time indexed everywhere
    H8 bWh[8], bWx[8];
    {
        const unsigned short* ph = Whh + (size_t)(l * 64 + w * 16 + g) * 4096 + (size_t)lane * 8;
        const unsigned short* px = Wxh + (size_t)(l * 64 + w * 16 + g) * 4096 + (size_t)lane * 8;
#pragma unroll
        for (int kc = 0; kc < 8; ++kc) {
            bWh[kc].q = *(const uint4*)(ph + (size_t)kc * 512);
            bWx[kc].q = *(const uint4*)(px + (size_t)kc * 512);
        }
    }
    float bgv4[4];
#pragma unroll
    for (int gam = 0; gam < 4; ++gam) bgv4[gam] = bgp2[l * ND4 + gam * 256 + dglob];

    float c_ = 0.f, n_ = 0.f, m_ = 0.f;

    u64* Xl = Xbuf + (size_t)l * 2 * 2048;
    u64* RnO = Rn + (size_t)l * PRD * 2048;               // used when l<3
    u64* RfO = Rf + (size_t)l * PRD * 4096;
    const u64* RnI = Rn + (size_t)(l > 0 ? l - 1 : 0) * PRD * 2048;  // used when l>0
    const u64* RfI = Rf + (size_t)(l > 0 ? l - 1 : 0) * PRD * 4096;

    // publisher slot (even-sd publishes pair (dglob,dglob+1)); R4-proven layout
    const size_t pubIdx = (size_t)(g >> 1) * 256 + (size_t)((dglob >> 3) & 3) * 64 +
                          (size_t)sb * 4 + ((sd >> 1) & 3);
    const bool doPub = (sd & 1) == 0;
    const size_t rdB = (size_t)quad * 64 + (size_t)mm * 4;
    const size_t rfIdx = (size_t)sb * 256 + dglob;

    const unsigned* consP = prog + (l + 1);
    unsigned consC = 0;
    unsigned* myProg = prog + l;
    const float* hembRow = hemb + (size_t)mm * SS * DD;   // A-row source (l==0)
    const float* hembHin = hemb + (size_t)sb * SS * DD + dglob;
    float* houtP = hout + (size_t)sb * SS * DD + dglob;
    __syncthreads();

    for (int t = 0; t < SS; ++t) {
        const unsigned tagT = (unsigned)(t + 1);
        // ---------- 1. acquire r[l-1][t] as fp16 A-frags + fp32 hin ----------
        H8 rfrag[8];
        float hin;
        if (l == 0) {
            const float* hp = hembRow + (size_t)t * DD + quad * 8;
#pragma unroll
            for (int kc = 0; kc < 8; ++kc) {
                float4 f0 = *(const float4*)(hp + kc * 32);
                float4 f1 = *(const float4*)(hp + kc * 32 + 4);
                rfrag[kc].v[0] = (_Float16)f0.x; rfrag[kc].v[1] = (_Float16)f0.y;
                rfrag[kc].v[2] = (_Float16)f0.z; rfrag[kc].v[3] = (_Float16)f0.w;
                rfrag[kc].v[4] = (_Float16)f1.x; rfrag[kc].v[5] = (_Float16)f1.y;
                rfrag[kc].v[6] = (_Float16)f1.z; rfrag[kc].v[7] = (_Float16)f1.w;
            }
            hin = hembHin[(size_t)t * DD];
        } else {
            const u64* Rp = RnI + (size_t)(t & (PRD - 1)) * 2048;
            const u64* Rfp = RfI + (size_t)(t & (PRD - 1)) * 4096 + rfIdx;
            u64 v[32], hv;
            int guard = 0;
            for (;;) {
#pragma unroll
                for (int kc = 0; kc < 8; ++kc)
#pragma unroll
                    for (int p = 0; p < 4; ++p)
                        v[kc * 4 + p] = aload(Rp + (size_t)kc * 256 + rdB + p);
                hv = aload(Rfp);
                bool ok = ((unsigned)(hv >> 32) == tagT);
#pragma unroll
                for (int i = 0; i < 32; ++i) ok &= ((unsigned)(v[i] >> 32) == tagT);
                if (ok) break;
                if (spinBail(guard, abortFlag)) break;
            }
#pragma unroll
            for (int kc = 0; kc < 8; ++kc)
#pragma unroll
                for (int p = 0; p < 4; ++p) rfrag[kc].u[p] = (unsigned)v[kc * 4 + p];
            hin = __uint_as_float((unsigned)hv);
        }
        // ---------- 2. LN stats (lane's 64 elems + quad shfl; fp32) ----------
        float s = 0.f, ss = 0.f;
#pragma unroll
        for (int kc = 0; kc < 8; ++kc)
#pragma unroll
            for (int i = 0; i < 8; ++i) {
                float xv = (float)rfrag[kc].v[i];
                s += xv; ss = fmaf(xv, xv, ss);
            }
        s += __shfl_xor(s, 16); ss += __shfl_xor(ss, 16);
        s += __shfl_xor(s, 32); ss += __shfl_xor(ss, 32);
        float mu = s * (1.f / 256.f);
        float rs = rsqrtf(fmaxf(ss * (1.f / 256.f) - mu * mu, 0.f) + 1e-5f);
        // ---------- 3. z = (r-mu)*rs (packed fp16), Wx' MFMAs ----------
        _Float16 muh = (_Float16)mu, rsh = (_Float16)rs;
        half8 mus = {muh, muh, muh, muh, muh, muh, muh, muh};
        half8 rss = {rsh, rsh, rsh, rsh, rsh, rsh, rsh, rsh};
        f32x4 acc0 = {0.f, 0.f, 0.f, 0.f}, acc1 = {0.f, 0.f, 0.f, 0.f};
#pragma unroll
        for (int kc = 0; kc < 8; kc += 2) {
            H8 z0, z1;
            z0.v = (rfrag[kc].v - mus) * rss;
            z1.v = (rfrag[kc + 1].v - mus) * rss;
            acc0 = __builtin_amdgcn_mfma_f32_16x16x32_f16(z0.v, bWx[kc].v, acc0, 0, 0, 0);
            acc1 = __builtin_amdgcn_mfma_f32_16x16x32_f16(z1.v, bWx[kc + 1].v, acc1, 0, 0, 0);
        }
        // ---------- 4. X rendezvous (h_s(t-1)) + Wh MFMAs ----------
        if (t > 0) {
            const unsigned tg = (unsigned)t;
            const u64* Xp = Xl + (size_t)(t & 1) * 2048;
            u64 v[32];
            int guard = 0;
            for (;;) {
#pragma unroll
                for (int kc = 0; kc < 8; ++kc)
#pragma unroll
                    for (int p = 0; p < 4; ++p)
                        v[kc * 4 + p] = aload(Xp + (size_t)kc * 256 + rdB + p);
                bool ok = true;
#pragma unroll
                for (int i = 0; i < 32; ++i) ok &= ((unsigned)(v[i] >> 32) == tg);
                if (ok) break;
                if ((++guard & 127) == 0) {
                    if (guard > (1 << 18) || aflag(abortFlag)) { sflag(abortFlag); break; }
                }
            }
            H8 afr[8];
#pragma unroll
            for (int kc = 0; kc < 8; ++kc)
#pragma unroll
                for (int p = 0; p < 4; ++p) afr[kc].u[p] = (unsigned)v[kc * 4 + p];
#pragma unroll
            for (int kc = 0; kc < 8; kc += 2) {
                acc0 = __builtin_amdgcn_mfma_f32_16x16x32_f16(afr[kc].v, bWh[kc].v, acc0, 0, 0, 0);
                acc1 = __builtin_amdgcn_mfma_f32_16x16x32_f16(afr[kc + 1].v, bWh[kc + 1].v, acc1, 0, 0, 0);
            }
        }
        f32x4 acc = acc0 + acc1;
        // ---------- 5. gbuf exchange (parity dbuf, one barrier) ----------
        const int par = t & 1;
#pragma unroll
        for (int r = 0; r < 4; ++r) gbuf[par][w][quad * 4 + r][mm] = acc[r];
        __syncthreads();
        // ---------- 6. gates (thread = (sb,sd)) ----------
        float gi = gbuf[par][0][sb][sd] + bgv4[0];
        float gf = gbuf[par][1][sb][sd] + bgv4[1];
        float gz = gbuf[par][2][sb][sd] + bgv4[2];
        float go = gbuf[par][3][sb][sd] + bgv4[3];
        float mn = fmaxf(gf + m_, gi);
        float ip = __expf(gi - mn);
        float fp = __expf(gf + m_ - mn);
        float e2z = __expf(2.f * gz);
        float th = 1.f - 2.f * __builtin_amdgcn_rcpf(e2z + 1.f);
        c_ = fp * c_ + ip * th;
        n_ = fp * n_ + ip;
        m_ = mn;
        float sg = __builtin_amdgcn_rcpf(1.f + __expf(-go));
        float hval = sg * c_ * __builtin_amdgcn_rcpf(fmaxf(fabsf(n_), 1.f));
        float rnew = hin + hval;
        // ---------- 7. publish: X first (partners' critical path) ----------
        float hodd = __shfl_down(hval, 1);
        float rodd = __shfl_down(rnew, 1);
        if (doPub) {
            unsigned payX = (unsigned)f16b(hval) | ((unsigned)f16b(hodd) << 16);
            astore(Xl + (size_t)((t + 1) & 1) * 2048 + pubIdx, ((u64)tagT << 32) | payX);
        }
        if (l == 3) {
            houtP[(size_t)t * DD] = rnew;
        } else {
            if (t >= PRD) {
                unsigned need = (unsigned)(t - PRD + 2);
                if (consC < need) {
                    int guard = 0;
                    for (;;) {
                        consC = pload(consP);
                        if (consC >= need) break;
                        if (spinBail(guard, abortFlag)) break;
                    }
                }
            }
            const size_t slot = (size_t)(t & (PRD - 1));
            if (doPub) {
                unsigned payR = (unsigned)f16b(rnew) | ((unsigned)f16b(rodd) << 16);
                astore(RnO + slot * 2048 + pubIdx, ((u64)tagT << 32) | payR);
            }
            astore(RfO + slot * 4096 + rfIdx, ((u64)tagT << 32) | (u64)__float_as_uint(rnew));
        }
        if (g == 0 && tid == 0) pstore(myProg, tagT);
    }
}

// ---------------------------------------------------------------------------
// final: out[b] = r3[b][S-1][:] . fc_W + fc_b
// ---------------------------------------------------------------------------
__global__ void final_kernel(const float* __restrict__ h, const float* __restrict__ fcW,
                             const float* __restrict__ fcb, float* __restrict__ out) {
    int b = blockIdx.x, lane = threadIdx.x;
    const float4 hv = *(const float4*)(h + ((size_t)b * SS + (SS - 1)) * DD + lane * 4);
    const float4 wv = *(const float4*)(fcW + lane * 4);
    float s = hv.x * wv.x + hv.y * wv.y + hv.z * wv.z + hv.w * wv.w;
#pragma unroll
    for (int off = 32; off; off >>= 1) s += __shfl_down(s, off);
    if (lane == 0) out[b] = s + fcb[0];
}

// ---------------------------------------------------------------------------
extern "C" void kernel_launch(void* const* d_in, const int* in_sizes, int n_in,
                              void* d_out, int out_size, void* d_ws, size_t ws_size,
                              hipStream_t stream) {
    const float* x   = (const float*)d_in[0];
    const float* tf  = (const float*)d_in[1];
    const float* inW = (const float*)d_in[2];
    const float* inb = (const float*)d_in[3];
    const float* lng = (const float*)d_in[4];
    const float* lnb = (const float*)d_in[5];
    const float* Wx  = (const float*)d_in[6];
    const float* Wh  = (const float*)d_in[7];
    const float* bg  = (const float*)d_in[8];
    const float* fcW = (const float*)d_in[9];
    const float* fcb = (const float*)d_in[10];
    float* out = (float*)d_out;

    const size_t nTok = (size_t)BB * SS;
    float* hemb = (float*)d_ws;                                    // 8,388,608 f
    float* hout = hemb + nTok * DD;                                // 8,388,608 f
    unsigned short* Wxh = (unsigned short*)(hout + nTok * DD);     // 1,048,576 us
    unsigned short* Whh = Wxh + 1048576;                           // 1,048,576 us
    float* bgp2 = (float*)(Whh + 1048576);                         // 4096 f
    u64* Xbuf = (u64*)(bgp2 + 4096);                               // 4*2*2048 u64
    u64* Rn = Xbuf + 4 * 2 * 2048;                                 // 3*PRD*2048 u64
    u64* Rf = Rn + 3 * PRD * 2048;                                 // 3*PRD*4096 u64
    unsigned* prog = (unsigned*)(Rf + 3 * PRD * 4096);             // 8 u32
    int* abortFlag = (int*)(prog + 8);

    const size_t needed = (size_t)((char*)(abortFlag + 1) - (char*)d_ws);
    if (ws_size < needed) return;  // fail visibly instead of corrupting

    hipMemsetAsync(prog, 0, 8 * sizeof(unsigned) + sizeof(int), stream);
    // X/Rn/Rf need no init: 0xAA poison never matches a tag in [1,2048]

    embed_kernel<<<nTok, DD, 0, stream>>>(x, tf, inW, inb, hemb);
    wprep_wh_kernel<<<256, 64, 0, stream>>>(Wh, Whh);
    wprep_wx_kernel<<<256, 64, 0, stream>>>(Wx, lng, Wxh);
    bgprep_kernel<<<16, 256, 0, stream>>>(bg, lnb, Wx, bgp2);
    mega_kernel<<<64, 256, 0, stream>>>(hemb, Whh, Wxh, bgp2, hout,
                                        Xbuf, Rn, Rf, prog, abortFlag);
    final_kernel<<<BB, 64, 0, stream>>>(hout, fcW, fcb, out);
    (void)in_sizes; (void)n_in; (void)out_size;
}

// Round 9
// 9282.793 us; speedup vs baseline: 3.5704x; 1.0117x over previous
//
#include <hip/hip_runtime.h>

// Problem constants
#define BB 16
#define SS 2048
#define DD 256
#define ND4 1024   // 4*D
#define PRD 16     // R-stream slot depth

typedef __attribute__((ext_vector_type(8))) _Float16 half8;
typedef __attribute__((ext_vector_type(4))) float f32x4;
typedef unsigned long long u64;
union H8 { half8 v; unsigned u[4]; uint4 q; };

__device__ __forceinline__ u64 aload(const u64* p) {
    return __hip_atomic_load(p, __ATOMIC_RELAXED, __HIP_MEMORY_SCOPE_AGENT);
}
__device__ __forceinline__ void astore(u64* p, u64 v) {
    __hip_atomic_store(p, v, __ATOMIC_RELAXED, __HIP_MEMORY_SCOPE_AGENT);
}
__device__ __forceinline__ unsigned pload(const unsigned* p) {
    return __hip_atomic_load(p, __ATOMIC_RELAXED, __HIP_MEMORY_SCOPE_AGENT);
}
__device__ __forceinline__ void pstore(unsigned* p, unsigned v) {
    __hip_atomic_store(p, v, __ATOMIC_RELAXED, __HIP_MEMORY_SCOPE_AGENT);
}
__device__ __forceinline__ int aflag(int* p) {
    return __hip_atomic_load(p, __ATOMIC_RELAXED, __HIP_MEMORY_SCOPE_AGENT);
}
__device__ __forceinline__ void sflag(int* p) {
    __hip_atomic_store(p, 1, __ATOMIC_RELAXED, __HIP_MEMORY_SCOPE_AGENT);
}
__device__ __forceinline__ unsigned short f16b(float x) {
    union { _Float16 h; unsigned short u; } c; c.h = (_Float16)x; return c.u;
}
__device__ __forceinline__ bool spinBail(int& guard, int* af) {
    if ((++guard & 63) == 0) {
        __builtin_amdgcn_s_sleep(1);
        if (guard > (1 << 18) || aflag(af)) { sflag(af); return true; }
    }
    return false;
}

// ---------------------------------------------------------------------------
// embed: h0 = [x | tf] @ in_W + in_b
// ---------------------------------------------------------------------------
__global__ void embed_kernel(const float* __restrict__ x, const float* __restrict__ tf,
                             const float* __restrict__ inW, const float* __restrict__ inb,
                             float* __restrict__ h) {
    int tok = blockIdx.x, d = threadIdx.x;
    float xv = x[tok];
    float acc = inb[d] + xv * inW[d];
#pragma unroll
    for (int c = 0; c < 6; ++c)
        acc = fmaf(tf[tok * 6 + c], inW[(c + 1) * DD + d], acc);
    h[(size_t)tok * DD + d] = acc;
}

// ---------------------------------------------------------------------------
// Wh -> fp16 B-fragment order (layout validated R4/R7/R8)
// ---------------------------------------------------------------------------
__global__ void wprep_wh_kernel(const float* __restrict__ W, unsigned short* __restrict__ Wo) {
    int l = blockIdx.x >> 6, G = blockIdx.x & 63;
    int lane = threadIdx.x, quad = lane >> 4, mm = lane & 15;
    const float* Wl = W + (size_t)l * DD * ND4;
    unsigned short* o = Wo + (size_t)blockIdx.x * 4096;
#pragma unroll
    for (int kc = 0; kc < 8; ++kc) {
        __align__(16) unsigned short tmp[8];
#pragma unroll
        for (int i = 0; i < 8; ++i)
            tmp[i] = f16b(Wl[(size_t)(kc * 32 + quad * 8 + i) * ND4 + G * 16 + mm]);
        *(uint4*)(o + ((size_t)kc * 64 + lane) * 8) = *(uint4*)tmp;
    }
}

// ---------------------------------------------------------------------------
// Wx' = diag(ln_g) @ Wx -> fp16 B-fragment order (gamma folded, R8-proven)
// ---------------------------------------------------------------------------
__global__ void wprep_wx_kernel(const float* __restrict__ W, const float* __restrict__ lng,
                                unsigned short* __restrict__ Wo) {
    int l = blockIdx.x >> 6, G = blockIdx.x & 63;
    int lane = threadIdx.x, quad = lane >> 4, mm = lane & 15;
    const float* Wl = W + (size_t)l * DD * ND4;
    const float* gl = lng + l * DD;
    unsigned short* o = Wo + (size_t)blockIdx.x * 4096;
#pragma unroll
    for (int kc = 0; kc < 8; ++kc) {
        __align__(16) unsigned short tmp[8];
#pragma unroll
        for (int i = 0; i < 8; ++i) {
            int k = kc * 32 + quad * 8 + i;
            tmp[i] = f16b(gl[k] * Wl[(size_t)k * ND4 + G * 16 + mm]);
        }
        *(uint4*)(o + ((size_t)kc * 64 + lane) * 8) = *(uint4*)tmp;
    }
}

// ---------------------------------------------------------------------------
// bg' = bg + ln_b @ Wx  (beta folded; fp32 exact)
// ---------------------------------------------------------------------------
__global__ void bgprep_kernel(const float* __restrict__ bg, const float* __restrict__ lnb,
                              const float* __restrict__ Wx, float* __restrict__ bgp2) {
    int idx = blockIdx.x * 256 + threadIdx.x;
    int l = idx >> 10, col = idx & 1023;
    const float* Wl = Wx + (size_t)l * DD * ND4;
    const float* bl = lnb + l * DD;
    float acc = bg[idx];
    for (int d = 0; d < DD; ++d) acc = fmaf(bl[d], Wl[(size_t)d * ND4 + col], acc);
    bgp2[idx] = acc;
}

// ---------------------------------------------------------------------------
// Mega kernel R9: software-pipelined fused scan (R8 structure + key change):
//   The Wx half (R acquire, LN, z-build, 4 Wx-MFMAs) for step t+1 executes
//   AFTER publishing X(t) — in the rendezvous shadow. Iteration t starts
//   directly at the X poll. Carried state: zacc (f32x4 x2) + hinCur.
//   Slot-reuse proof: prog stored at iteration END (after tail prefetch),
//   so producer gate prog>=T-14 covers the consumer's early r(T-16) read.
// XCD remap (perf-only): l=(bid&7)>>1, g=(bid>>3)*2+(bid&1) — each layer's
//   16 WGs land on 2 XCDs under round-robin %8 placement.
// ---------------------------------------------------------------------------
__global__ __launch_bounds__(256, 1) void mega_kernel(
    const float* __restrict__ hemb, const unsigned short* __restrict__ Whh,
    const unsigned short* __restrict__ Wxh, const float* __restrict__ bgp2,
    float* __restrict__ hout,
    u64* __restrict__ Xbuf, u64* __restrict__ Rn, u64* __restrict__ Rf,
    unsigned* __restrict__ prog, int* __restrict__ abortFlag) {
    __shared__ float gbuf[2][4][16][18];
    const int bid = blockIdx.x;
    const int tid = threadIdx.x;
    const int l = (bid & 7) >> 1;                       // XCD-pair remap
    const int g = ((bid >> 3) << 1) | (bid & 1);
    const int w = tid >> 6, lane = tid & 63;
    const int mm = lane & 15, quad = lane >> 4;
    const int sb = tid >> 4, sd = tid & 15;
    const int dglob = g * 16 + sd;

    // B fragments (tile G = w*16+g), compile-time indexed (R6/R7 lesson)
    H8 bWh[8], bWx[8];
    {
        const unsigned short* ph = Whh + (size_t)(l * 64 + w * 16 + g) * 4096 + (size_t)lane * 8;
        const unsigned short* px = Wxh + (size_t)(l * 64 + w * 16 + g) * 4096 + (size_t)lane * 8;
#pragma unroll
        for (int kc = 0; kc < 8; ++kc) {
            bWh[kc].q = *(const uint4*)(ph + (size_t)kc * 512);
            bWx[kc].q = *(const uint4*)(px + (size_t)kc * 512);
        }
    }
    float bgv4[4];
#pragma unroll
    for (int gam = 0; gam < 4; ++gam) bgv4[gam] = bgp2[l * ND4 + gam * 256 + dglob];

    float c_ = 0.f, n_ = 0.f, m_ = 0.f;

    u64* Xl = Xbuf + (size_t)l * 2 * 2048;
    u64* RnO = Rn + (size_t)l * PRD * 2048;
    u64* RfO = Rf + (size_t)l * PRD * 4096;
    const u64* RnI = Rn + (size_t)(l > 0 ? l - 1 : 0) * PRD * 2048;
    const u64* RfI = Rf + (size_t)(l > 0 ? l - 1 : 0) * PRD * 4096;

    const size_t pubIdx = (size_t)(g >> 1) * 256 + (size_t)((dglob >> 3) & 3) * 64 +
                          (size_t)sb * 4 + ((sd >> 1) & 3);
    const bool doPub = (sd & 1) == 0;
    const size_t rdB = (size_t)quad * 64 + (size_t)mm * 4;
    const size_t rfIdx = (size_t)sb * 256 + dglob;

    const unsigned* consP = prog + (l + 1);
    unsigned consC = 0;
    unsigned* myProg = prog + l;
    const float* hembRow = hemb + (size_t)mm * SS * DD;
    const float* hembHin = hemb + (size_t)sb * SS * DD + dglob;
    float* houtP = hout + (size_t)sb * SS * DD + dglob;

    // carried pipeline state: zWx(t) accumulators + hin(t)
    f32x4 zacc0, zacc1;
    float hinCur = 0.f;

    // prefetch+compute for step tt (fills zacc/hinCur); tt < SS guaranteed
    auto prefetchZ = [&](int tt) {
        const unsigned tg = (unsigned)(tt + 1);
        H8 rfrag[8];
        if (l == 0) {
            const float* hp = hembRow + (size_t)tt * DD + quad * 8;
#pragma unroll
            for (int kc = 0; kc < 8; ++kc) {
                float4 f0 = *(const float4*)(hp + kc * 32);
                float4 f1 = *(const float4*)(hp + kc * 32 + 4);
                rfrag[kc].v[0] = (_Float16)f0.x; rfrag[kc].v[1] = (_Float16)f0.y;
                rfrag[kc].v[2] = (_Float16)f0.z; rfrag[kc].v[3] = (_Float16)f0.w;
                rfrag[kc].v[4] = (_Float16)f1.x; rfrag[kc].v[5] = (_Float16)f1.y;
                rfrag[kc].v[6] = (_Float16)f1.z; rfrag[kc].v[7] = (_Float16)f1.w;
            }
            hinCur = hembHin[(size_t)tt * DD];
        } else {
            const u64* Rp = RnI + (size_t)(tt & (PRD - 1)) * 2048;
            const u64* Rfp = RfI + (size_t)(tt & (PRD - 1)) * 4096 + rfIdx;
            u64 v[32], hv;
            int guard = 0;
            for (;;) {
#pragma unroll
                for (int kc = 0; kc < 8; ++kc)
#pragma unroll
                    for (int p = 0; p < 4; ++p)
                        v[kc * 4 + p] = aload(Rp + (size_t)kc * 256 + rdB + p);
                hv = aload(Rfp);
                bool ok = ((unsigned)(hv >> 32) == tg);
#pragma unroll
                for (int i = 0; i < 32; ++i) ok &= ((unsigned)(v[i] >> 32) == tg);
                if (ok) break;
                if (spinBail(guard, abortFlag)) break;
            }
#pragma unroll
            for (int kc = 0; kc < 8; ++kc)
#pragma unroll
                for (int p = 0; p < 4; ++p) rfrag[kc].u[p] = (unsigned)v[kc * 4 + p];
            hinCur = __uint_as_float((unsigned)hv);
        }
        // LN stats (lane's 64 elems + quad shfl)
        float s = 0.f, ss = 0.f;
#pragma unroll
        for (int kc = 0; kc < 8; ++kc)
#pragma unroll
            for (int i = 0; i < 8; ++i) {
                float xv = (float)rfrag[kc].v[i];
                s += xv; ss = fmaf(xv, xv, ss);
            }
        s += __shfl_xor(s, 16); ss += __shfl_xor(ss, 16);
        s += __shfl_xor(s, 32); ss += __shfl_xor(ss, 32);
        float mu = s * (1.f / 256.f);
        float rs = rsqrtf(fmaxf(ss * (1.f / 256.f) - mu * mu, 0.f) + 1e-5f);
        _Float16 muh = (_Float16)mu, rsh = (_Float16)rs;
        half8 mus = {muh, muh, muh, muh, muh, muh, muh, muh};
        half8 rss = {rsh, rsh, rsh, rsh, rsh, rsh, rsh, rsh};
        f32x4 a0 = {0.f, 0.f, 0.f, 0.f}, a1 = {0.f, 0.f, 0.f, 0.f};
#pragma unroll
        for (int kc = 0; kc < 8; kc += 2) {
            H8 z0, z1;
            z0.v = (rfrag[kc].v - mus) * rss;
            z1.v = (rfrag[kc + 1].v - mus) * rss;
            a0 = __builtin_amdgcn_mfma_f32_16x16x32_f16(z0.v, bWx[kc].v, a0, 0, 0, 0);
            a1 = __builtin_amdgcn_mfma_f32_16x16x32_f16(z1.v, bWx[kc + 1].v, a1, 0, 0, 0);
        }
        zacc0 = a0; zacc1 = a1;
    };

    __syncthreads();
    prefetchZ(0);   // fill pipeline for t=0

    for (int t = 0; t < SS; ++t) {
        const unsigned tagT = (unsigned)(t + 1);
        f32x4 acc0 = zacc0, acc1 = zacc1;
        // ---------- 1. X rendezvous (the only step-serial dependency) ----------
        if (t > 0) {
            const unsigned tg = (unsigned)t;
            const u64* Xp = Xl + (size_t)(t & 1) * 2048;
            u64 v[32];
            int guard = 0;
            for (;;) {
#pragma unroll
                for (int kc = 0; kc < 8; ++kc)
#pragma unroll
                    for (int p = 0; p < 4; ++p)
                        v[kc * 4 + p] = aload(Xp + (size_t)kc * 256 + rdB + p);
                bool ok = true;
#pragma unroll
                for (int i = 0; i < 32; ++i) ok &= ((unsigned)(v[i] >> 32) == tg);
                if (ok) break;
                if ((++guard & 127) == 0) {
                    if (guard > (1 << 18) || aflag(abortFlag)) { sflag(abortFlag); break; }
                }
            }
            H8 afr[8];
#pragma unroll
            for (int kc = 0; kc < 8; ++kc)
#pragma unroll
                for (int p = 0; p < 4; ++p) afr[kc].u[p] = (unsigned)v[kc * 4 + p];
#pragma unroll
            for (int kc = 0; kc < 8; kc += 2) {
                acc0 = __builtin_amdgcn_mfma_f32_16x16x32_f16(afr[kc].v, bWh[kc].v, acc0, 0, 0, 0);
                acc1 = __builtin_amdgcn_mfma_f32_16x16x32_f16(afr[kc + 1].v, bWh[kc + 1].v, acc1, 0, 0, 0);
            }
        }
        f32x4 acc = acc0 + acc1;
        // ---------- 2. gbuf exchange (parity dbuf, one barrier) ----------
        const int par = t & 1;
#pragma unroll
        for (int r = 0; r < 4; ++r) gbuf[par][w][quad * 4 + r][mm] = acc[r];
        __syncthreads();
        // ---------- 3. gates ----------
        float gi = gbuf[par][0][sb][sd] + bgv4[0];
        float gf = gbuf[par][1][sb][sd] + bgv4[1];
        float gz = gbuf[par][2][sb][sd] + bgv4[2];
        float go = gbuf[par][3][sb][sd] + bgv4[3];
        float mn = fmaxf(gf + m_, gi);
        float ip = __expf(gi - mn);
        float fp = __expf(gf + m_ - mn);
        float e2z = __expf(2.f * gz);
        float th = 1.f - 2.f * __builtin_amdgcn_rcpf(e2z + 1.f);
        c_ = fp * c_ + ip * th;
        n_ = fp * n_ + ip;
        m_ = mn;
        float sg = __builtin_amdgcn_rcpf(1.f + __expf(-go));
        float hval = sg * c_ * __builtin_amdgcn_rcpf(fmaxf(fabsf(n_), 1.f));
        float rnew = hinCur + hval;
        // ---------- 4. publish X FIRST (partners' critical path) ----------
        float hodd = __shfl_down(hval, 1);
        float rodd = __shfl_down(rnew, 1);
        if (doPub) {
            unsigned payX = (unsigned)f16b(hval) | ((unsigned)f16b(hodd) << 16);
            astore(Xl + (size_t)((t + 1) & 1) * 2048 + pubIdx, ((u64)tagT << 32) | payX);
        }
        // ---------- 5. residual out (downstream critical path) ----------
        if (l == 3) {
            houtP[(size_t)t * DD] = rnew;
        } else {
            if (t >= PRD) {
                unsigned need = (unsigned)(t - PRD + 2);
                if (consC < need) {
                    int guard = 0;
                    for (;;) {
                        consC = pload(consP);
                        if (consC >= need) break;
                        if (spinBail(guard, abortFlag)) break;
                    }
                }
            }
            const size_t slot = (size_t)(t & (PRD - 1));
            if (doPub) {
                unsigned payR = (unsigned)f16b(rnew) | ((unsigned)f16b(rodd) << 16);
                astore(RnO + slot * 2048 + pubIdx, ((u64)tagT << 32) | payR);
            }
            astore(RfO + slot * 4096 + rfIdx, ((u64)tagT << 32) | (u64)__float_as_uint(rnew));
        }
        // ---------- 6. rendezvous shadow: prefetch + zWx for step t+1 ----------
        if (t + 1 < SS) prefetchZ(t + 1);
        // ---------- 7. progress (AFTER tail prefetch: slot-reuse proof) ----------
        if (g == 0 && tid == 0) pstore(myProg, tagT);
    }
}

// ---------------------------------------------------------------------------
// final: out[b] = r3[b][S-1][:] . fc_W + fc_b
// ---------------------------------------------------------------------------
__global__ void final_kernel(const float* __restrict__ h, const float* __restrict__ fcW,
                             const float* __restrict__ fcb, float* __restrict__ out) {
    int b = blockIdx.x, lane = threadIdx.x;
    const float4 hv = *(const float4*)(h + ((size_t)b * SS + (SS - 1)) * DD + lane * 4);
    const float4 wv = *(const float4*)(fcW + lane * 4);
    float s = hv.x * wv.x + hv.y * wv.y + hv.z * wv.z + hv.w * wv.w;
#pragma unroll
    for (int off = 32; off; off >>= 1) s += __shfl_down(s, off);
    if (lane == 0) out[b] = s + fcb[0];
}

// ---------------------------------------------------------------------------
extern "C" void kernel_launch(void* const* d_in, const int* in_sizes, int n_in,
                              void* d_out, int out_size, void* d_ws, size_t ws_size,
                              hipStream_t stream) {
    const float* x   = (const float*)d_in[0];
    const float* tf  = (const float*)d_in[1];
    const float* inW = (const float*)d_in[2];
    const float* inb = (const float*)d_in[3];
    const float* lng = (const float*)d_in[4];
    const float* lnb = (const float*)d_in[5];
    const float* Wx  = (const float*)d_in[6];
    const float* Wh  = (const float*)d_in[7];
    const float* bg  = (const float*)d_in[8];
    const float* fcW = (const float*)d_in[9];
    const float* fcb = (const float*)d_in[10];
    float* out = (float*)d_out;

    const size_t nTok = (size_t)BB * SS;
    float* hemb = (float*)d_ws;
    float* hout = hemb + nTok * DD;
    unsigned short* Wxh = (unsigned short*)(hout + nTok * DD);
    unsigned short* Whh = Wxh + 1048576;
    float* bgp2 = (float*)(Whh + 1048576);
    u64* Xbuf = (u64*)(bgp2 + 4096);
    u64* Rn = Xbuf + 4 * 2 * 2048;
    u64* Rf = Rn + 3 * PRD * 2048;
    unsigned* prog = (unsigned*)(Rf + 3 * PRD * 4096);
    int* abortFlag = (int*)(prog + 8);

    const size_t needed = (size_t)((char*)(abortFlag + 1) - (char*)d_ws);
    if (ws_size < needed) return;

    hipMemsetAsync(prog, 0, 8 * sizeof(unsigned) + sizeof(int), stream);
    // X/Rn/Rf need no init: 0xAA poison never matches a tag in [1,2048]

    embed_kernel<<<nTok, DD, 0, stream>>>(x, tf, inW, inb, hemb);
    wprep_wh_kernel<<<256, 64, 0, stream>>>(Wh, Whh);
    wprep_wx_kernel<<<256, 64, 0, stream>>>(Wx, lng, Wxh);
    bgprep_kernel<<<16, 256, 0, stream>>>(bg, lnb, Wx, bgp2);
    mega_kernel<<<64, 256, 0, stream>>>(hemb, Whh, Wxh, bgp2, hout,
                                        Xbuf, Rn, Rf, prog, abortFlag);
    final_kernel<<<BB, 64, 0, stream>>>(hout, fcW, fcb, out);
    (void)in_sizes; (void)n_in; (void)out_size;
}